// Round 3
// baseline (41.070 us; speedup 1.0000x reference)
//
#include <hip/hip_runtime.h>

#define EMBED_DIM 64
#define BATCH 16384
#define K_NBR 50

#define RPB 16          // rows (batch items) per block
#define THREADS 512     // 8 waves: 2 k-groups x 4 waves

__global__ __launch_bounds__(THREADS, 8) void kgat_fused_kernel(
    const int* __restrict__ item_idx,      // [B]
    const int* __restrict__ nbr_idx,       // [B, K]
    const float* __restrict__ item_tab,    // [NUM_ITEMS, D]
    const float* __restrict__ ent_tab,     // [NUM_ENTITIES, D]
    const float* __restrict__ W,           // [D, D] row-major: W[j][d]
    const float* __restrict__ bias,        // [D]
    float* __restrict__ out)               // [B, D]
{
    __shared__ int   ids[RPB * K_NBR];                    // 3.2 KB
    __shared__ int   itid[RPB];                           // 64 B
    __shared__ float xsp[2][RPB][EMBED_DIM + 4];          // 8.7 KB partial sums
    __shared__ float Wl[EMBED_DIM][EMBED_DIM + 1];        // 16.25 KB, (j+d)%32 banks

    const int t    = threadIdx.x;
    const int lane = t & 63;
    const int wave = t >> 6;                 // 0..7
    const int g    = wave >> 2;              // k-group 0/1
    const int w    = wave & 3;               // wave-in-group 0..3
    const int row0 = blockIdx.x * RPB;

    // ---- stage W, neighbor ids, item ids into LDS (coalesced, once) ----
    #pragma unroll
    for (int i = t; i < EMBED_DIM * EMBED_DIM; i += THREADS)
        Wl[i >> 6][i & 63] = W[i];
    #pragma unroll
    for (int i = t; i < RPB * K_NBR; i += THREADS)
        ids[i] = nbr_idx[(size_t)row0 * K_NBR + i];
    if (t < RPB) itid[t] = item_idx[row0 + t];
    __syncthreads();

    // ---- phase 1: float4 gather, k split across 2 groups ----
    // wave covers 4 rows: q = row-in-group (lane>>4), c = dim-quad (lane&15)
    {
        const int q = lane >> 4;
        const int c = lane & 15;
        const int r = w * 4 + q;             // local row 0..15
        const int idbase = r * K_NBR;
        const int k0 = g * (K_NBR / 2);      // 0 or 25
        const int k1 = k0 + (K_NBR / 2);

        const float4* __restrict__ ent4  = (const float4*)ent_tab;
        const float4* __restrict__ item4 = (const float4*)item_tab;

        float4 acc = make_float4(0.f, 0.f, 0.f, 0.f);

        #pragma unroll 5
        for (int k = k0; k < k1; ++k) {
            const int idx = ids[idbase + k];            // LDS broadcast
            const float4 v = ent4[(size_t)idx * (EMBED_DIM / 4) + c];
            acc.x += v.x; acc.y += v.y; acc.z += v.z; acc.w += v.w;
        }

        const float s = 1.0f / K_NBR;
        float4 x;
        if (g == 0) {
            const int it = itid[r];
            const float4 iv = item4[(size_t)it * (EMBED_DIM / 4) + c];
            x.x = fmaf(acc.x, s, iv.x);
            x.y = fmaf(acc.y, s, iv.y);
            x.z = fmaf(acc.z, s, iv.z);
            x.w = fmaf(acc.w, s, iv.w);
        } else {
            x.x = acc.x * s; x.y = acc.y * s; x.z = acc.z * s; x.w = acc.w * s;
        }
        *(float4*)&xsp[g][r][c * 4] = x;
    }

    __syncthreads();

    // ---- phase 2: y[r][j] = relu( sum_d (xsp0+xsp1)[r][d] * W[j][d] + b[j] ) ----
    // thread t: j = lane, rows {wave, wave+8}
    {
        const int j = lane;
        const int r0 = wave;
        float a0 = 0.f, a1 = 0.f;

        #pragma unroll
        for (int d = 0; d < EMBED_DIM; ++d) {
            const float wv = Wl[j][d];                       // (j+d)%32: 2-way, free
            const float x0 = xsp[0][r0    ][d] + xsp[1][r0    ][d];  // broadcasts
            const float x1 = xsp[0][r0 + 8][d] + xsp[1][r0 + 8][d];
            a0 = fmaf(x0, wv, a0);
            a1 = fmaf(x1, wv, a1);
        }

        const float bb = bias[j];
        out[(size_t)(row0 + r0    ) * EMBED_DIM + j] = fmaxf(a0 + bb, 0.f);
        out[(size_t)(row0 + r0 + 8) * EMBED_DIM + j] = fmaxf(a1 + bb, 0.f);
    }
}

extern "C" void kernel_launch(void* const* d_in, const int* in_sizes, int n_in,
                              void* d_out, int out_size, void* d_ws, size_t ws_size,
                              hipStream_t stream) {
    const int*   item_idx = (const int*)  d_in[0];
    const int*   nbr_idx  = (const int*)  d_in[1];
    const float* item_tab = (const float*)d_in[2];
    const float* ent_tab  = (const float*)d_in[3];
    const float* W        = (const float*)d_in[4];
    const float* bias     = (const float*)d_in[5];
    float*       out      = (float*)      d_out;

    dim3 grid(BATCH / RPB);   // 1024 blocks, 4 per CU, 32 waves/CU
    dim3 block(THREADS);
    kgat_fused_kernel<<<grid, block, 0, stream>>>(
        item_idx, nbr_idx, item_tab, ent_tab, W, bias, out);
}